// Round 9
// baseline (937.576 us; speedup 1.0000x reference)
//
#include <hip/hip_runtime.h>

#define NN 2048
#define NE 8192
#define ED 10
#define EH 32
#define HID 160
#define NCOL 5504   // 32*160 (w2) + 160 (b2) + 160 (root) + 64 zero-pad
#define NB 512      // persistent grid: guaranteed resident (cap >= 1024)

typedef __attribute__((ext_vector_type(8))) short short8;
typedef __attribute__((ext_vector_type(4))) float f32x4;
typedef unsigned int u32;

__device__ __forceinline__ ushort f2bf(float v) {   // RNE
    u32 u = __float_as_uint(v);
    u += 0x7FFF + ((u >> 16) & 1);
    return (ushort)(u >> 16);
}
__device__ __forceinline__ float bf2f(ushort u) {
    return __uint_as_float(((u32)u) << 16);
}
__device__ __forceinline__ void gl2lds16(const ushort* g, ushort* l) {
    __builtin_amdgcn_global_load_lds(
        (const __attribute__((address_space(1))) u32*)g,
        (__attribute__((address_space(3))) u32*)l, 16, 0, 0);
}

// device-scope grid barrier (sense via monotonically increasing generation)
__device__ __forceinline__ void gbar(int* cnt, int* gen, int target) {
    __syncthreads();
    if (threadIdx.x == 0) {
        int arrived = __hip_atomic_fetch_add(cnt, 1, __ATOMIC_ACQ_REL,
                                             __HIP_MEMORY_SCOPE_AGENT) + 1;
        if (arrived == NB) {
            __hip_atomic_store(cnt, 0, __ATOMIC_RELAXED, __HIP_MEMORY_SCOPE_AGENT);
            __hip_atomic_store(gen, target, __ATOMIC_RELEASE, __HIP_MEMORY_SCOPE_AGENT);
        } else {
            while (__hip_atomic_load(gen, __ATOMIC_ACQUIRE,
                                     __HIP_MEMORY_SCOPE_AGENT) < target)
                __builtin_amdgcn_s_sleep(2);
        }
    }
    __syncthreads();
}

struct Params {
    const float *x, *ea;
    const float *w1a, *b1a, *w2a, *b2a, *roota, *biasa;
    const float *w1b, *b1b, *w2b, *b2b, *rootb, *biasb;
    const int* ei;
    float* out;
    ushort *G, *BtA, *BtB, *xb0, *xn;
    float *h_a, *h_b, *dinv;
    int *doff, *degg, *delist;
    int *bcnt, *bgen;
};

// ================== single persistent mega-kernel ==================
// phases: prep (1177 tasks) | 3x [ gemm (688 tiles) | aggr (2048 dsts) ]
__global__ __launch_bounds__(256, 4) void k_mega(Params P) {
    __shared__ char smem[20608];
    const int bid = blockIdx.x, t = threadIdx.x;

    // ---------------- phase 0: prep ----------------
    for (int task = bid; task < 1177; task += NB) {
        if (task < 512) {                // edge MLP, 4 elems/thread
            int set = task >> 8, rel = task & 255;
            const float* w1 = set ? P.w1b : P.w1a;
            const float* b1 = set ? P.b1b : P.b1a;
            float* h = set ? P.h_b : P.h_a;
            int idx = rel * 1024 + t * 4;
            int e = idx >> 5, j0 = idx & 31;
            float o4[4];
#pragma unroll
            for (int u = 0; u < 4; ++u) {
                float acc = b1[j0 + u];
#pragma unroll
                for (int i = 0; i < ED; ++i)
                    acc += P.ea[e * ED + i] * w1[i * EH + j0 + u];
                o4[u] = fmaxf(acc, 0.f);
            }
            *(float4*)&h[idx] = *(const float4*)o4;
        } else if (task < 856) {         // Bt[n][k] bf16 via LDS transpose
            int rel = task - 512;
            int set = rel / 172, pb = rel - set * 172;
            float (*tile)[161] = (float(*)[161])smem;
            const float* w2 = set ? P.w2b : P.w2a;
            const float* b2 = set ? P.b2b : P.b2a;
            const float* root = set ? P.rootb : P.roota;
            ushort* Bt = set ? P.BtB : P.BtA;
            const float* src;
            int n0, zero = 0;
            if (pb < 160)      { int q = pb / 5, op = pb - q * 5; n0 = q * 160 + op * 32; src = w2 + q * 25600 + op * 32; }
            else if (pb < 165) { int ip = pb - 160; n0 = 5120 + ip * 32; src = b2 + ip * 32; }
            else if (pb < 170) { int ip = pb - 165; n0 = 5280 + ip * 32; src = root + ip * 32; }
            else               { n0 = 5440 + (pb - 170) * 32; src = b2; zero = 1; }
            int kl = t >> 5, ol = t & 31;
#pragma unroll
            for (int pass = 0; pass < 20; ++pass) {
                int k = pass * 8 + kl;
                tile[ol][k] = zero ? 0.f : src[k * HID + ol];
            }
            __syncthreads();
            int on = t >> 3, j = t & 7;
            int n = n0 + on;
#pragma unroll
            for (int i = 0; i < 20; i += 2) {
                int k = j * 20 + i;
                u32 pk = ((u32)f2bf(tile[on][k + 1]) << 16) | f2bf(tile[on][k]);
                *(u32*)&Bt[(size_t)n * HID + k] = pk;
            }
        } else if (task < 1176) {        // x -> bf16
            int idx = (task - 856) * 1024 + t * 4;
            float4 xv = *(const float4*)&P.x[idx];
            ushort o4[4] = {f2bf(xv.x), f2bf(xv.y), f2bf(xv.z), f2bf(xv.w)};
            *(u32*)&P.xb0[idx] = *(const u32*)&o4[0];
            *(u32*)&P.xb0[idx + 2] = *(const u32*)&o4[2];
        } else {                         // CSR build over dst (one block)
            int* deg = (int*)smem;
            int* cur = deg + NN;
            int* part = cur + NN;
            for (int i = t; i < NN; i += 256) deg[i] = 0;
            __syncthreads();
            for (int e = t; e < NE; e += 256) atomicAdd(&deg[P.ei[NE + e]], 1);
            __syncthreads();
            int loc[8], s = 0;
#pragma unroll
            for (int i = 0; i < 8; ++i) { loc[i] = s; s += deg[t * 8 + i]; }
            part[t] = s;
            __syncthreads();
            int tot = s;
            for (int st = 1; st < 256; st <<= 1) {
                int v = (t >= st) ? part[t - st] : 0;
                __syncthreads();
                part[t] += v;
                __syncthreads();
            }
            int base = part[t] - tot;
#pragma unroll
            for (int i = 0; i < 8; ++i) {
                int d = t * 8 + i;
                P.doff[d] = base + loc[i];
                cur[d] = base + loc[i];
                P.degg[d] = deg[d];
                P.dinv[d] = 1.0f / fmaxf((float)deg[d], 1.0f);
            }
            __syncthreads();
            for (int e = t; e < NE; e += 256) {
                int d = P.ei[NE + e];
                int pp = atomicAdd(&cur[d], 1);
                P.delist[pp] = e;
            }
        }
        __syncthreads();                 // protect smem reuse across tasks
    }
    gbar(P.bcnt, P.bgen, 1);

    // ---------------- 3 layers ----------------
    for (int layer = 0; layer < 3; ++layer) {
        const ushort* A = layer ? P.xn : P.xb0;
        const ushort* Bt = layer ? P.BtB : P.BtA;
        const float* h = layer ? P.h_b : P.h_a;
        const float* bias = layer ? P.biasb : P.biasa;
        int last = (layer == 2);

        // ---- gemm: G = A @ Bt^T, bf16 MFMA, 128x128 tiles ----
        {
            ushort* sA = (ushort*)smem;            // 8 KB
            ushort* sB = (ushort*)(smem + 8192);   // 8 KB
            for (int task = bid; task < 688; task += NB) {
                int bn = (task % 43) * 128, bm = (task / 43) * 128;
                int wid = t >> 6, lane = t & 63;
                int wm = (wid >> 1) * 64, wn = (wid & 1) * 64;
                int lr = lane & 15, lk = lane >> 4;
                f32x4 acc[4][4];
#pragma unroll
                for (int i = 0; i < 4; ++i)
#pragma unroll
                    for (int j = 0; j < 4; ++j) acc[i][j] = (f32x4){0.f, 0.f, 0.f, 0.f};
                for (int c = 0; c < 5; ++c) {
                    int k0 = c * 32;
#pragma unroll
                    for (int i = 0; i < 2; ++i) {
                        int s = t + i * 256;
                        int r = s >> 2, go = (s & 3) * 8;
                        gl2lds16(&A[(size_t)(bm + r) * HID + k0 + go], &sA[s * 8]);
                        gl2lds16(&Bt[(size_t)(bn + r) * HID + k0 + go], &sB[s * 8]);
                    }
                    __syncthreads();
                    short8 av[4];
#pragma unroll
                    for (int mt = 0; mt < 4; ++mt)
                        av[mt] = *(const short8*)&sA[(wm + mt * 16 + lr) * 32 + lk * 8];
#pragma unroll
                    for (int nt = 0; nt < 4; ++nt) {
                        short8 bv = *(const short8*)&sB[(wn + nt * 16 + lr) * 32 + lk * 8];
#pragma unroll
                        for (int mt = 0; mt < 4; ++mt)
                            acc[mt][nt] = __builtin_amdgcn_mfma_f32_16x16x32_bf16(av[mt], bv, acc[mt][nt], 0, 0, 0);
                    }
                    __syncthreads();
                }
#pragma unroll
                for (int mt = 0; mt < 4; ++mt)
#pragma unroll
                    for (int nt = 0; nt < 4; ++nt) {
                        int m0 = bm + wm + mt * 16 + lk * 4;
                        int n = bn + wn + nt * 16 + lr;
#pragma unroll
                        for (int r = 0; r < 4; ++r)
                            P.G[(size_t)(m0 + r) * NCOL + n] = f2bf(acc[mt][nt][r]);
                    }
            }
        }
        gbar(P.bcnt, P.bgen, 2 + 2 * layer);

        // ---- aggr: dst-grouped, fused mean+root+bias+relu+cvt ----
        {
            float* hbuf = (float*)smem;            // 16*32 floats
            int* ebuf = (int*)(smem + 2048);
            int* sbuf = ebuf + 16;
            for (int d = bid; d < NN; d += NB) {
                int o0 = P.doff[d], dg = P.degg[d];
                float acc = 0.f;
                for (int c0 = 0; c0 < dg; c0 += 16) {
                    int nc = min(16, dg - c0);
                    if (t < nc) {
                        int e = P.delist[o0 + c0 + t];
                        ebuf[t] = e;
                        sbuf[t] = P.ei[e];
                    }
                    __syncthreads();
                    for (int i = t; i < nc * EH; i += 256)
                        hbuf[i] = h[ebuf[i >> 5] * EH + (i & 31)];
                    __syncthreads();
                    if (t < HID) {
                        for (int j = 0; j < nc; ++j) {
                            const ushort* Gr = P.G + (size_t)sbuf[j] * NCOL;
                            const float* hj = &hbuf[j * EH];
                            float a = bf2f(Gr[5120 + t]);
#pragma unroll
                            for (int q = 0; q < 32; ++q)
                                a += hj[q] * bf2f(Gr[q * HID + t]);
                            acc += a;
                        }
                    }
                    __syncthreads();
                }
                if (t < HID) {
                    float v = acc * P.dinv[d] + bf2f(P.G[(size_t)d * NCOL + 5280 + t]) + bias[t];
                    if (last) P.out[d * HID + t] = v;
                    else      P.xn[d * HID + t] = f2bf(fmaxf(v, 0.f));
                }
                __syncthreads();
            }
        }
        if (!last) gbar(P.bcnt, P.bgen, 3 + 2 * layer);
    }
}

extern "C" void kernel_launch(void* const* d_in, const int* in_sizes, int n_in,
                              void* d_out, int out_size, void* d_ws, size_t ws_size,
                              hipStream_t stream) {
    Params P;
    P.x     = (const float*)d_in[0];
    P.ea    = (const float*)d_in[1];
    P.w1a   = (const float*)d_in[2];
    P.b1a   = (const float*)d_in[3];
    P.w2a   = (const float*)d_in[4];
    P.b2a   = (const float*)d_in[5];
    P.roota = (const float*)d_in[6];
    P.biasa = (const float*)d_in[7];
    P.w1b   = (const float*)d_in[8];
    P.b1b   = (const float*)d_in[9];
    P.w2b   = (const float*)d_in[10];
    P.b2b   = (const float*)d_in[11];
    P.rootb = (const float*)d_in[12];
    P.biasb = (const float*)d_in[13];
    P.ei    = (const int*)d_in[14];
    P.out   = (float*)d_out;

    char* p = (char*)d_ws;
    P.bcnt = (int*)p;
    P.bgen = (int*)p + 1;  p += 256;                       // barrier flags
    P.G = (ushort*)p;      p += (size_t)NN * NCOL * 2;     // 22.5 MB
    P.BtA = (ushort*)p;    p += (size_t)NCOL * HID * 2;
    P.BtB = (ushort*)p;    p += (size_t)NCOL * HID * 2;
    P.h_a = (float*)p;     p += (size_t)NE * EH * 4;
    P.h_b = (float*)p;     p += (size_t)NE * EH * 4;
    P.xb0 = (ushort*)p;    p += (size_t)NN * HID * 2;
    P.xn = (ushort*)p;     p += (size_t)NN * HID * 2;
    P.doff = (int*)p;      p += NN * 4;
    P.degg = (int*)p;      p += NN * 4;
    P.dinv = (float*)p;    p += NN * 4;
    P.delist = (int*)p;    p += NE * 4;

    hipMemsetAsync(d_ws, 0, 256, stream);                  // zero barrier flags
    k_mega<<<NB, 256, 0, stream>>>(P);
}

// Round 10
// 201.747 us; speedup vs baseline: 4.6473x; 4.6473x over previous
//
#include <hip/hip_runtime.h>

#define NN 2048
#define NE 8192
#define ED 10
#define EH 32
#define HID 160
#define NCOL 5504   // 32*160 (w2) + 160 (b2) + 160 (root) + 64 zero-pad

typedef __attribute__((ext_vector_type(8))) short short8;
typedef __attribute__((ext_vector_type(4))) float f32x4;
typedef unsigned int u32;

__device__ __forceinline__ ushort f2bf(float v) {   // RNE
    u32 u = __float_as_uint(v);
    u += 0x7FFF + ((u >> 16) & 1);
    return (ushort)(u >> 16);
}
__device__ __forceinline__ float bf2f(ushort u) {
    return __uint_as_float(((u32)u) << 16);
}
__device__ __forceinline__ void gl2lds16(const ushort* g, ushort* l) {
    __builtin_amdgcn_global_load_lds(
        (const __attribute__((address_space(1))) u32*)g,
        (__attribute__((address_space(3))) u32*)l, 16, 0, 0);
}

// ---- Bt panel transpose (ushort LDS tile, 10.8 KB), 172 panels per set ----
__device__ __forceinline__ void bt_panel(int pb, const float* w2, const float* b2,
                                         const float* root, ushort* Bt,
                                         char* smem, int t) {
    ushort (*tile)[168] = (ushort(*)[168])smem;
    const float* src;
    int n0, zero = 0;
    if (pb < 160)      { int q = pb / 5, op = pb - q * 5; n0 = q * 160 + op * 32; src = w2 + q * 25600 + op * 32; }
    else if (pb < 165) { int ip = pb - 160; n0 = 5120 + ip * 32; src = b2 + ip * 32; }
    else if (pb < 170) { int ip = pb - 165; n0 = 5280 + ip * 32; src = root + ip * 32; }
    else               { n0 = 5440 + (pb - 170) * 32; src = b2; zero = 1; }
    int kl = t >> 5, ol = t & 31;
#pragma unroll
    for (int pass = 0; pass < 20; ++pass) {
        int k = pass * 8 + kl;
        tile[ol][k] = zero ? (ushort)0 : f2bf(src[k * HID + ol]);
    }
    __syncthreads();
    int on = t >> 3, j = t & 7;
    int n = n0 + on;
#pragma unroll
    for (int i = 0; i < 20; i += 2) {
        int k = j * 20 + i;
        u32 pk = ((u32)tile[on][k + 1] << 16) | tile[on][k];
        *(u32*)&Bt[(size_t)n * HID + k] = pk;
    }
}

// ---- one 128x128 G tile: G = A @ Bt^T, bf16 MFMA (R7-proven body) ----
__device__ __forceinline__ void gemm_tile(int task, const ushort* A,
                                          const ushort* Bt, ushort* G,
                                          char* smem, int t) {
    ushort* sA = (ushort*)smem;            // 8 KB
    ushort* sB = (ushort*)(smem + 8192);   // 8 KB
    int bn = (task % 43) * 128, bm = (task / 43) * 128;
    int wid = t >> 6, lane = t & 63;
    int wm = (wid >> 1) * 64, wn = (wid & 1) * 64;
    int lr = lane & 15, lk = lane >> 4;
    f32x4 acc[4][4];
#pragma unroll
    for (int i = 0; i < 4; ++i)
#pragma unroll
        for (int j = 0; j < 4; ++j) acc[i][j] = (f32x4){0.f, 0.f, 0.f, 0.f};
    for (int c = 0; c < 5; ++c) {
        int k0 = c * 32;
#pragma unroll
        for (int i = 0; i < 2; ++i) {
            int s = t + i * 256;
            int r = s >> 2, go = (s & 3) * 8;
            gl2lds16(&A[(size_t)(bm + r) * HID + k0 + go], &sA[s * 8]);
            gl2lds16(&Bt[(size_t)(bn + r) * HID + k0 + go], &sB[s * 8]);
        }
        __syncthreads();
        short8 av[4];
#pragma unroll
        for (int mt = 0; mt < 4; ++mt)
            av[mt] = *(const short8*)&sA[(wm + mt * 16 + lr) * 32 + lk * 8];
#pragma unroll
        for (int nt = 0; nt < 4; ++nt) {
            short8 bv = *(const short8*)&sB[(wn + nt * 16 + lr) * 32 + lk * 8];
#pragma unroll
            for (int mt = 0; mt < 4; ++mt)
                acc[mt][nt] = __builtin_amdgcn_mfma_f32_16x16x32_bf16(av[mt], bv, acc[mt][nt], 0, 0, 0);
        }
        __syncthreads();
    }
#pragma unroll
    for (int mt = 0; mt < 4; ++mt)
#pragma unroll
        for (int nt = 0; nt < 4; ++nt) {
            int m0 = bm + wm + mt * 16 + lk * 4;
            int n = bn + wn + nt * 16 + lr;
#pragma unroll
            for (int r = 0; r < 4; ++r)
                G[(size_t)(m0 + r) * NCOL + n] = f2bf(acc[mt][nt][r]);
        }
}

// ---- prep1: x->bf16 (320 blocks) + BtA transpose (172 blocks) ----
__global__ __launch_bounds__(256) void k_prep1(
        const float* __restrict__ x, ushort* __restrict__ xb,
        const float* __restrict__ w2a, const float* __restrict__ b2a,
        const float* __restrict__ roota, ushort* __restrict__ BtA) {
    __shared__ char smem[10752];
    int b = blockIdx.x, t = threadIdx.x;
    if (b < 320) {
        int idx = b * 1024 + t * 4;
        float4 xv = *(const float4*)&x[idx];
        ushort o4[4] = {f2bf(xv.x), f2bf(xv.y), f2bf(xv.z), f2bf(xv.w)};
        *(u32*)&xb[idx] = *(const u32*)&o4[0];
        *(u32*)&xb[idx + 2] = *(const u32*)&o4[2];
        return;
    }
    bt_panel(b - 320, w2a, b2a, roota, BtA, smem, t);
}

// ---- gemm layer1 + hidden prep: MLP (512), BtB (172), CSR (1) ----
__global__ __launch_bounds__(256) void k_gemmP(
        const ushort* __restrict__ A, const ushort* __restrict__ Bt,
        ushort* __restrict__ G, const float* __restrict__ ea,
        const float* __restrict__ w1a, const float* __restrict__ b1a,
        const float* __restrict__ w1b, const float* __restrict__ b1b,
        float* __restrict__ ha, float* __restrict__ hb,
        const float* __restrict__ w2b, const float* __restrict__ b2b,
        const float* __restrict__ rootb, ushort* __restrict__ BtB,
        const int* __restrict__ ei, int* __restrict__ doff,
        int* __restrict__ degg, float* __restrict__ dinv,
        int* __restrict__ delist) {
    __shared__ char smem[17408];
    int b = blockIdx.x, t = threadIdx.x;
    if (b < 688) { gemm_tile(b, A, Bt, G, smem, t); return; }
    if (b < 1200) {                      // edge MLP, 4 elems/thread
        int rel = b - 688;
        int set = rel >> 8;
        const float* w1 = set ? w1b : w1a;
        const float* b1 = set ? b1b : b1a;
        float* h = set ? hb : ha;
        int idx = (rel & 255) * 1024 + t * 4;
        int e = idx >> 5, j0 = idx & 31;
        float o4[4];
#pragma unroll
        for (int u = 0; u < 4; ++u) {
            float acc = b1[j0 + u];
#pragma unroll
            for (int i = 0; i < ED; ++i) acc += ea[e * ED + i] * w1[i * EH + j0 + u];
            o4[u] = fmaxf(acc, 0.f);
        }
        *(float4*)&h[idx] = *(const float4*)o4;
        return;
    }
    if (b < 1372) { bt_panel(b - 1200, w2b, b2b, rootb, BtB, smem, t); return; }
    // CSR build over dst (single block, 256 threads)
    int* deg = (int*)smem;
    int* cur = deg + NN;
    int* part = cur + NN;
    for (int i = t; i < NN; i += 256) deg[i] = 0;
    __syncthreads();
    for (int e = t; e < NE; e += 256) atomicAdd(&deg[ei[NE + e]], 1);
    __syncthreads();
    int loc[8], s = 0;
#pragma unroll
    for (int i = 0; i < 8; ++i) { loc[i] = s; s += deg[t * 8 + i]; }
    part[t] = s;
    __syncthreads();
    int tot = s;
    for (int st = 1; st < 256; st <<= 1) {
        int v = (t >= st) ? part[t - st] : 0;
        __syncthreads();
        part[t] += v;
        __syncthreads();
    }
    int base = part[t] - tot;
#pragma unroll
    for (int i = 0; i < 8; ++i) {
        int d = t * 8 + i;
        doff[d] = base + loc[i];
        cur[d] = base + loc[i];
        degg[d] = deg[d];
        dinv[d] = 1.0f / fmaxf((float)deg[d], 1.0f);
    }
    __syncthreads();
    for (int e = t; e < NE; e += 256) {
        int d = ei[NE + e];
        int pp = atomicAdd(&cur[d], 1);
        delist[pp] = e;
    }
}

// ---- gemm only (layers 2,3) ----
__global__ __launch_bounds__(256) void k_gemm(const ushort* __restrict__ A,
                                              const ushort* __restrict__ Bt,
                                              ushort* __restrict__ G) {
    __shared__ char smem[16384];
    gemm_tile(blockIdx.x, A, Bt, G, smem, threadIdx.x);
}

// ==== aggr: dst-grouped, vectorized G reads (b128/lane), fused epilogue ====
// thread t -> (qg = t/20: 4-q group, og = t%20: 8-o octet); 8 partials in regs
__global__ __launch_bounds__(160) void k_aggr(const ushort* __restrict__ G,
        const float* __restrict__ h, const int* __restrict__ ei,
        const int* __restrict__ doff, const int* __restrict__ degg,
        const float* __restrict__ dinv, const int* __restrict__ delist,
        const float* __restrict__ bias, ushort* __restrict__ xn,
        float* __restrict__ out, int last) {
    __shared__ float hbuf[16 * EH];
    __shared__ int ebuf[16], sbuf[16];
    __shared__ float red[8][168];
    int d = blockIdx.x, t = threadIdx.x;
    int og = t % 20, qg = t / 20;
    int o8 = og * 8;
    int o0 = doff[d], dg = degg[d];
    float acc[8];
#pragma unroll
    for (int r = 0; r < 8; ++r) acc[r] = 0.f;
    for (int c0 = 0; c0 < dg; c0 += 16) {
        int nc = min(16, dg - c0);
        if (t < nc) {
            int e = delist[o0 + c0 + t];
            ebuf[t] = e;
            sbuf[t] = ei[e];
        }
        __syncthreads();
        for (int i = t; i < nc * EH; i += 160)
            hbuf[i] = h[ebuf[i >> 5] * EH + (i & 31)];
        __syncthreads();
        for (int j = 0; j < nc; ++j) {
            const ushort* Gr = G + (size_t)sbuf[j] * NCOL;
            float4 hq = *(const float4*)&hbuf[j * EH + qg * 4];
            short8 v0 = *(const short8*)&Gr[(qg * 4 + 0) * HID + o8];
            short8 v1 = *(const short8*)&Gr[(qg * 4 + 1) * HID + o8];
            short8 v2 = *(const short8*)&Gr[(qg * 4 + 2) * HID + o8];
            short8 v3 = *(const short8*)&Gr[(qg * 4 + 3) * HID + o8];
#pragma unroll
            for (int r = 0; r < 8; ++r)
                acc[r] += hq.x * bf2f((ushort)v0[r]) + hq.y * bf2f((ushort)v1[r])
                        + hq.z * bf2f((ushort)v2[r]) + hq.w * bf2f((ushort)v3[r]);
            if (qg == 0) {               // b2 (xb) term, coefficient 1
                short8 vb = *(const short8*)&Gr[5120 + o8];
#pragma unroll
                for (int r = 0; r < 8; ++r) acc[r] += bf2f((ushort)vb[r]);
            }
        }
        __syncthreads();
    }
#pragma unroll
    for (int r = 0; r < 8; ++r) red[qg][o8 + r] = acc[r];
    __syncthreads();
    if (t < HID) {
        float s = red[0][t] + red[1][t] + red[2][t] + red[3][t]
                + red[4][t] + red[5][t] + red[6][t] + red[7][t];
        float v = s * dinv[d] + bf2f(G[(size_t)d * NCOL + 5280 + t]) + bias[t];
        if (last) out[d * HID + t] = v;
        else      xn[d * HID + t] = f2bf(fmaxf(v, 0.f));
    }
}

extern "C" void kernel_launch(void* const* d_in, const int* in_sizes, int n_in,
                              void* d_out, int out_size, void* d_ws, size_t ws_size,
                              hipStream_t stream) {
    const float* x     = (const float*)d_in[0];
    const float* ea    = (const float*)d_in[1];
    const float* w1a   = (const float*)d_in[2];
    const float* b1a   = (const float*)d_in[3];
    const float* w2a   = (const float*)d_in[4];
    const float* b2a   = (const float*)d_in[5];
    const float* roota = (const float*)d_in[6];
    const float* biasa = (const float*)d_in[7];
    const float* w1b   = (const float*)d_in[8];
    const float* b1b   = (const float*)d_in[9];
    const float* w2b   = (const float*)d_in[10];
    const float* b2b   = (const float*)d_in[11];
    const float* rootb = (const float*)d_in[12];
    const float* biasb = (const float*)d_in[13];
    const int*   ei    = (const int*)d_in[14];
    float* out = (float*)d_out;

    char* p = (char*)d_ws;
    ushort* G = (ushort*)p;    p += (size_t)NN * NCOL * 2;    // 22.5 MB
    ushort* BtA = (ushort*)p;  p += (size_t)NCOL * HID * 2;
    ushort* BtB = (ushort*)p;  p += (size_t)NCOL * HID * 2;
    float* h_a = (float*)p;    p += (size_t)NE * EH * 4;
    float* h_b = (float*)p;    p += (size_t)NE * EH * 4;
    ushort* xb0 = (ushort*)p;  p += (size_t)NN * HID * 2;
    ushort* xn = (ushort*)p;   p += (size_t)NN * HID * 2;
    int* doff = (int*)p;       p += NN * 4;
    int* degg = (int*)p;       p += NN * 4;
    float* dinv = (float*)p;   p += NN * 4;
    int* delist = (int*)p;     p += NE * 4;

    // 1: minimal prep for gemm1 (xb0 + BtA)
    k_prep1<<<492, 256, 0, stream>>>(x, xb0, w2a, b2a, roota, BtA);
    // 2: gemm layer1 + hidden prep (h_a, h_b, BtB, CSR)
    k_gemmP<<<1373, 256, 0, stream>>>(xb0, BtA, G, ea, w1a, b1a, w1b, b1b,
                                      h_a, h_b, w2b, b2b, rootb, BtB,
                                      ei, doff, degg, dinv, delist);
    // 3..7: aggr1, (gemm, aggr) x2
    k_aggr<<<NN, 160, 0, stream>>>(G, h_a, ei, doff, degg, dinv, delist,
                                   biasa, xn, out, 0);
    k_gemm<<<688, 256, 0, stream>>>(xn, BtB, G);
    k_aggr<<<NN, 160, 0, stream>>>(G, h_b, ei, doff, degg, dinv, delist,
                                   biasb, xn, out, 0);
    k_gemm<<<688, 256, 0, stream>>>(xn, BtB, G);
    k_aggr<<<NN, 160, 0, stream>>>(G, h_b, ei, doff, degg, dinv, delist,
                                   biasb, xn, out, 1);
}